// Round 3
// 314.379 us; speedup vs baseline: 1.0028x; 1.0028x over previous
//
#include <hip/hip_runtime.h>

// MultiSpectralDCTLayer: Y = W @ X @ W^T per (b,c) tile, then radial band mask.
// XOR bug in the mask => only c=0 (s<196) and c=1 (s>=196) keep entries, where
// s = (i^2)+(j^2) with ^ = bitwise XOR. Groups 2..63 are constant 1e-8.
//
// Grid layout: 512 compute blocks first (128 tiles x 4 row-chunks of 28 rows),
// then 3968 pure-fill blocks. One kernel so fill writes overlap compute.
// LDS 64512 B -> 2 blocks/CU.
//
// R3 = R1 with the nontemporal-store compile fix: __builtin_nontemporal_store
// needs a NATIVE clang vector type (ext_vector_type), not HIP's float4 class.
//  - all output stores nontemporal (190 MB of fills are never re-read; keep
//    them from churning L2 against concurrent compute-block X/W reads)
//  - fill loop: 12 unconditional stores + explicit 64-thread tail
//  - phase 2: W row loads as float4 (dwordx4 guaranteed, 448 -> 112 loads/thread)

#define SIZE  112
#define TILE  (SIZE * SIZE)    // 12544
#define TILE4 (TILE / 4)       // 3136
#define NCOMPUTE 512
#define FILLV 1e-8f

typedef float f32x4 __attribute__((ext_vector_type(4)));   // native vec for nt stores

#define DOT4(a, b) ((a).x*(b).x + (a).y*(b).y + (a).z*(b).z + (a).w*(b).w)

// u += wscal * xv  (wscal = one component of a W float4)
#define ACC4(u, ws, xv) \
    (u).x += (ws) * (xv).x; (u).y += (ws) * (xv).y; \
    (u).z += (ws) * (xv).z; (u).w += (ws) * (xv).w;

__global__ __launch_bounds__(256)
void dct_band_kernel(const float* __restrict__ x,
                     const float* __restrict__ W,
                     float* __restrict__ out)
{
    const int tid = threadIdx.x;
    const int blk = blockIdx.x;

    if (blk >= NCOMPUTE) {
        // ---- pure fill: groups c>=2 are 1e-8 everywhere ----
        const int f = blk - NCOMPUTE;
        const int b = f / 62;
        const int c = 2 + (f - b * 62);
        f32x4* o4 = (f32x4*)(out + (size_t)(b * 64 + c) * TILE);
        const f32x4 v = {FILLV, FILLV, FILLV, FILLV};
        #pragma unroll
        for (int n = 0; n < 12; ++n)
            __builtin_nontemporal_store(v, o4 + tid + n * 256);
        if (tid < 64)
            __builtin_nontemporal_store(v, o4 + tid + 12 * 256);   // 12*256+64 = 3136
        return;
    }

    // ---- compute path ----
    // regA: phase 1 = Xs[k][l4] (row stride 28 float4s, 3136 used)
    //       phase 3 = Wb[jq*113 + m*28 + l4] = W[4*jq+m][4*l4..4*l4+3] (3164 used)
    __shared__ float4 regA[3248];   // 51968 B
    __shared__ float4 Usm[784];     // U[di][l4], row stride 28 float4s; 12544 B

    const int q  = blk & 3;          // row chunk: rows i0..i0+27
    const int t  = blk >> 2;         // tile 0..127
    const int b  = t >> 1;
    const int c  = t & 1;
    const int i0 = 28 * q;
    const size_t tOff = (size_t)(b * 64 + c) * TILE;

    // phase 1: X tile -> LDS (coalesced float4)
    const float4* x4 = (const float4*)(x + tOff);
    #pragma unroll
    for (int n = 0; n < 13; ++n) {
        int e = tid + n * 256;
        if (e < TILE4) regA[e] = x4[e];
    }
    __syncthreads();

    // phase 2 (stage A): U[i0+di][l] = sum_k W[i0+di][k] * X[k][l]
    // thread = (diq, l4): 4 di rows x 4 l cols; 7*28 = 196 active threads.
    // W rows loaded as float4 (rows contiguous: row r at W + r*112 = 28 float4s).
    if (tid < 196) {
        const int diq = tid / 28;
        const int l4  = tid % 28;
        float4 u0 = make_float4(0,0,0,0), u1 = u0, u2 = u0, u3 = u0;
        const float4* wq = (const float4*)(W + (i0 + 4 * diq) * SIZE);
        #pragma unroll 2
        for (int k4 = 0; k4 < 28; ++k4) {
            const float4 w0v = wq[k4];           // W[row0][4k4..4k4+3]
            const float4 w1v = wq[k4 + 28];
            const float4 w2v = wq[k4 + 56];
            const float4 w3v = wq[k4 + 84];
            const float4 xv0 = regA[(4 * k4 + 0) * 28 + l4];
            const float4 xv1 = regA[(4 * k4 + 1) * 28 + l4];
            const float4 xv2 = regA[(4 * k4 + 2) * 28 + l4];
            const float4 xv3 = regA[(4 * k4 + 3) * 28 + l4];
            ACC4(u0, w0v.x, xv0); ACC4(u0, w0v.y, xv1);
            ACC4(u0, w0v.z, xv2); ACC4(u0, w0v.w, xv3);
            ACC4(u1, w1v.x, xv0); ACC4(u1, w1v.y, xv1);
            ACC4(u1, w1v.z, xv2); ACC4(u1, w1v.w, xv3);
            ACC4(u2, w2v.x, xv0); ACC4(u2, w2v.y, xv1);
            ACC4(u2, w2v.z, xv2); ACC4(u2, w2v.w, xv3);
            ACC4(u3, w3v.x, xv0); ACC4(u3, w3v.y, xv1);
            ACC4(u3, w3v.z, xv2); ACC4(u3, w3v.w, xv3);
        }
        const int ub = 4 * diq * 28 + l4;
        Usm[ub]          = u0;
        Usm[ub + 28]     = u1;
        Usm[ub + 56]     = u2;
        Usm[ub + 84]     = u3;
    }
    __syncthreads();  // all Xs reads done, U complete

    // phase 3: W -> LDS in quad-row-swizzled padded layout (overwrites Xs)
    const float4* W4 = (const float4*)W;
    #pragma unroll
    for (int n = 0; n < 13; ++n) {
        int e = tid + n * 256;
        if (e < TILE4) {
            int j = e / 28;              // W row
            int p = e % 28;              // l4
            regA[(j >> 2) * 113 + (j & 3) * 28 + p] = W4[e];
        }
    }
    __syncthreads();

    // phase 4 (stage B): Y[i][j] = sum_l U[i][l] * W[j][l], then mask + store
    if (tid < 196) {
        const int dq = tid / 28;         // di quad 0..6
        const int jq = tid % 28;         // j quad 0..27
        float acc[4][4];
        #pragma unroll
        for (int a = 0; a < 4; ++a)
            #pragma unroll
            for (int d = 0; d < 4; ++d) acc[a][d] = 0.f;

        const float4* Ur = Usm + 4 * dq * 28;
        const float4* Wb = regA + jq * 113;
        #pragma unroll 2
        for (int l = 0; l < 28; ++l) {
            float4 u0 = Ur[l], u1 = Ur[l + 28], u2 = Ur[l + 56], u3 = Ur[l + 84];
            float4 w0 = Wb[l], w1 = Wb[l + 28], w2 = Wb[l + 56], w3 = Wb[l + 84];
            acc[0][0] += DOT4(u0, w0); acc[0][1] += DOT4(u0, w1);
            acc[0][2] += DOT4(u0, w2); acc[0][3] += DOT4(u0, w3);
            acc[1][0] += DOT4(u1, w0); acc[1][1] += DOT4(u1, w1);
            acc[1][2] += DOT4(u1, w2); acc[1][3] += DOT4(u1, w3);
            acc[2][0] += DOT4(u2, w0); acc[2][1] += DOT4(u2, w1);
            acc[2][2] += DOT4(u2, w2); acc[2][3] += DOT4(u2, w3);
            acc[3][0] += DOT4(u3, w0); acc[3][1] += DOT4(u3, w1);
            acc[3][2] += DOT4(u3, w2); acc[3][3] += DOT4(u3, w3);
        }

        const int j0 = 4 * jq;
        const bool g1 = (c != 0);
        #pragma unroll
        for (int mi = 0; mi < 4; ++mi) {
            const int i  = i0 + 4 * dq + mi;
            const int xi = i ^ 2;
            f32x4 res;
            res.x = (((xi + ((j0 + 0) ^ 2)) < 196) != g1) ? acc[mi][0] : FILLV;
            res.y = (((xi + ((j0 + 1) ^ 2)) < 196) != g1) ? acc[mi][1] : FILLV;
            res.z = (((xi + ((j0 + 2) ^ 2)) < 196) != g1) ? acc[mi][2] : FILLV;
            res.w = (((xi + ((j0 + 3) ^ 2)) < 196) != g1) ? acc[mi][3] : FILLV;
            f32x4* orow = (f32x4*)(out + tOff + (size_t)i * SIZE);
            __builtin_nontemporal_store(res, orow + jq);
        }
    }
}

extern "C" void kernel_launch(void* const* d_in, const int* in_sizes, int n_in,
                              void* d_out, int out_size, void* d_ws, size_t ws_size,
                              hipStream_t stream) {
    const float* x = (const float*)d_in[0];
    const float* W = (const float*)d_in[1];
    float* out = (float*)d_out;
    (void)in_sizes; (void)n_in; (void)out_size; (void)d_ws; (void)ws_size;
    dct_band_kernel<<<dim3(NCOMPUTE + 64 * 62), dim3(256), 0, stream>>>(x, W, out);
}